// Round 1
// baseline (829.273 us; speedup 1.0000x reference)
//
#include <hip/hip_runtime.h>
#include <cmath>

// ---------------------------------------------------------------------------
// Classifier: feats = F@W_b^T + b; o1 = feats@W1^T; sm1 = masked_softmax(o1);
// aug = feats + sm1@centroid; x = normalize(aug); o2 = x@W2^T/0.05; sm2 = softmax(o2)
//
// d_out layout (floats):
//   feats   [8192,1024] @ 0
//   aug     [8192,1024] @ 8388608
//   o1      [8192,1000] @ 16777216
//   o2      [8192,1000] @ 24969216
//   softmax [8192,1000] @ 33161216          total 41353216
// Scratch (inside d_out, dead by final write):
//   sm1  [8192,1024] @ 24969216 (o2+softmax slots; consumed by GEMM3 before o2 write)
//   cT   [1024,1024] @ 33357824 (inside softmax slot; consumed before softmax2)
//   invn [8192]      @ 34406400 (inside softmax slot)
// ---------------------------------------------------------------------------

typedef _Float16 h8 __attribute__((ext_vector_type(8)));
typedef _Float16 h4 __attribute__((ext_vector_type(4)));
typedef float f32x4 __attribute__((ext_vector_type(4)));

constexpr int BM = 128, BN = 128, BK = 32, LDH = 40; // LDH: padded halves/row (bank-conflict pad, keeps 16B align)

// MODE 1: feats   = A@B^T + bias(aux)            [fp16x2, 3-term]
// MODE 2: o1      = A@B^T, store cols<nC         [fp16x2, 3-term]
// MODE 3: aug     = A@B^T + aux[row,col]         [fp16x1]
// MODE 4: o2      = ((A*invn[row])@B^T)*20       [fp16x1]
template <int MODE>
__global__ __launch_bounds__(256) void gemm_kernel(
    const float* __restrict__ A, int lda,
    const float* __restrict__ B, int ldb, int nB, int K,
    float* __restrict__ C, int ldc, int nC,
    const float* __restrict__ aux, const float* __restrict__ invn)
{
    constexpr bool PREC2 = (MODE <= 2);
    __shared__ _Float16 sA[BM * LDH];
    __shared__ _Float16 sB[BN * LDH];
    __shared__ _Float16 sAlo[PREC2 ? BM * LDH : 1];
    __shared__ _Float16 sBlo[PREC2 ? BN * LDH : 1];

    const int t = threadIdx.x;
    const int row0 = blockIdx.y * BM;
    const int col0 = blockIdx.x * BN;
    const int lane = t & 63;
    const int wid = t >> 6;
    const int wr = wid >> 1, wc = wid & 1;    // 2x2 waves, 64x64 out each
    const int fr = lane & 15;                 // fragment row/col (A-m / B-n / D-col)
    const int fk = (lane >> 4) * 8;           // fragment k offset

    f32x4 acc[4][4] = {};
    f32x4 accc[4][4] = {};                    // cross terms (x2048); dead if !PREC2

    for (int k0 = 0; k0 < K; k0 += BK) {
        // ---- stage A (fp32 -> fp16 hi/lo) ----
        #pragma unroll
        for (int it = 0; it < 4; ++it) {
            int idx = (it * 256 + t) * 4;
            int r = idx >> 5, c = idx & 31;
            int gr = row0 + r;
            f32x4 v = *(const f32x4*)(A + (size_t)gr * lda + (k0 + c));
            if constexpr (MODE == 4) v = v * invn[gr];
            h4 hi, lo;
            #pragma unroll
            for (int j = 0; j < 4; ++j) {
                float x = v[j];
                _Float16 h = (_Float16)x;
                hi[j] = h;
                if constexpr (PREC2) lo[j] = (_Float16)((x - (float)h) * 2048.0f);
            }
            *(h4*)&sA[r * LDH + c] = hi;
            if constexpr (PREC2) *(h4*)&sAlo[r * LDH + c] = lo;
        }
        // ---- stage B (row-guarded: nB may be 1000) ----
        #pragma unroll
        for (int it = 0; it < 4; ++it) {
            int idx = (it * 256 + t) * 4;
            int r = idx >> 5, c = idx & 31;
            int gn = col0 + r;
            f32x4 v = {0.f, 0.f, 0.f, 0.f};
            if (gn < nB) v = *(const f32x4*)(B + (size_t)gn * ldb + (k0 + c));
            h4 hi, lo;
            #pragma unroll
            for (int j = 0; j < 4; ++j) {
                float x = v[j];
                _Float16 h = (_Float16)x;
                hi[j] = h;
                if constexpr (PREC2) lo[j] = (_Float16)((x - (float)h) * 2048.0f);
            }
            *(h4*)&sB[r * LDH + c] = hi;
            if constexpr (PREC2) *(h4*)&sBlo[r * LDH + c] = lo;
        }
        __syncthreads();
        // ---- compute ----
        h8 a_hi[4], a_lo[4];
        #pragma unroll
        for (int mf = 0; mf < 4; ++mf) {
            int rr = wr * 64 + mf * 16 + fr;
            a_hi[mf] = *(const h8*)&sA[rr * LDH + fk];
            if constexpr (PREC2) a_lo[mf] = *(const h8*)&sAlo[rr * LDH + fk];
        }
        #pragma unroll
        for (int nf = 0; nf < 4; ++nf) {
            int cc = wc * 64 + nf * 16 + fr;
            h8 b_hi = *(const h8*)&sB[cc * LDH + fk];
            h8 b_lo;
            if constexpr (PREC2) b_lo = *(const h8*)&sBlo[cc * LDH + fk];
            #pragma unroll
            for (int mf = 0; mf < 4; ++mf) {
                acc[mf][nf] = __builtin_amdgcn_mfma_f32_16x16x32_f16(a_hi[mf], b_hi, acc[mf][nf], 0, 0, 0);
                if constexpr (PREC2) {
                    accc[mf][nf] = __builtin_amdgcn_mfma_f32_16x16x32_f16(a_hi[mf], b_lo, accc[mf][nf], 0, 0, 0);
                    accc[mf][nf] = __builtin_amdgcn_mfma_f32_16x16x32_f16(a_lo[mf], b_hi, accc[mf][nf], 0, 0, 0);
                }
            }
        }
        __syncthreads();
    }
    // ---- epilogue (C/D layout: col=lane&15, row=(lane>>4)*4+j  [m89-verified]) ----
    #pragma unroll
    for (int mf = 0; mf < 4; ++mf) {
        #pragma unroll
        for (int nf = 0; nf < 4; ++nf) {
            f32x4 v = acc[mf][nf];
            if constexpr (PREC2) v = v + accc[mf][nf] * (1.0f / 2048.0f);
            int gcol = col0 + wc * 64 + nf * 16 + fr;
            int rbase = row0 + wr * 64 + mf * 16 + (lane >> 4) * 4;
            #pragma unroll
            for (int j = 0; j < 4; ++j) {
                int grow = rbase + j;
                float val = v[j];
                if constexpr (MODE == 1) val += aux[gcol];
                if constexpr (MODE == 3) val += aux[(size_t)grow * 1024 + gcol];
                if constexpr (MODE == 4) val *= 20.0f;
                if (gcol < nC) C[(size_t)grow * ldc + gcol] = val;
            }
        }
    }
}

// cT[n*1024+k] = k<1000 ? centroid[k*1024+n] : 0   (NT-ify centroid, pad K to 1024)
__global__ void centroidT_kernel(const float* __restrict__ centroid, float* __restrict__ cT)
{
    int idx = blockIdx.x * 256 + threadIdx.x;
    int n = idx >> 10;
    int k = idx & 1023;
    cT[idx] = (k < 1000) ? centroid[(size_t)k * 1024 + n] : 0.0f;
}

// masked softmax (mask_mechanism): one block per row
__global__ __launch_bounds__(256) void masksm_kernel(const float* __restrict__ o1, float* __restrict__ sm)
{
    const int row = blockIdx.x;
    const int t = threadIdx.x;
    const float* x = o1 + (size_t)row * 1000;
    float* y = sm + (size_t)row * 1024;

    float bv = -1e30f; int bi = 0;
    for (int c = t; c < 1000; c += 256) {
        float v = x[c];
        if (v > bv) { bv = v; bi = c; }   // first-occurrence argmax (ascending scan)
    }
    #pragma unroll
    for (int off = 32; off > 0; off >>= 1) {
        float ov = __shfl_down(bv, off, 64);
        int   oi = __shfl_down(bi, off, 64);
        if (ov > bv || (ov == bv && oi < bi)) { bv = ov; bi = oi; }
    }
    __shared__ float wv[4]; __shared__ int wi[4];
    __shared__ float s_m, s_tot; __shared__ int s_p;
    const int lane = t & 63, wid = t >> 6;
    if (lane == 0) { wv[wid] = bv; wi[wid] = bi; }
    __syncthreads();
    if (t == 0) {
        float mv = wv[0]; int mi = wi[0];
        for (int w = 1; w < 4; ++w)
            if (wv[w] > mv || (wv[w] == mv && wi[w] < mi)) { mv = wv[w]; mi = wi[w]; }
        s_p = mi; s_m = mv;
    }
    __syncthreads();
    const int p = s_p; const float m = s_m;  // m = x[p] (global max)
    if (p >= 500) {
        // row fully masked except predicted -> exact one-hot
        for (int c = t; c < 1024; c += 256) y[c] = (c == p) ? 1.0f : 0.0f;
    } else {
        // unmasked = {p} ∪ {500..999}; masked get exp(-1e9-m)=0 exactly
        float s = 0.f;
        for (int c = t; c < 1000; c += 256)
            if (c == p || c >= 500) s += expf(x[c] - m);
        #pragma unroll
        for (int off = 32; off > 0; off >>= 1) s += __shfl_down(s, off, 64);
        if (lane == 0) wv[wid] = s;
        __syncthreads();
        if (t == 0) s_tot = wv[0] + wv[1] + wv[2] + wv[3];
        __syncthreads();
        const float inv = 1.0f / s_tot;
        for (int c = t; c < 1024; c += 256) {
            float v = 0.f;
            if (c < 1000 && (c == p || c >= 500)) v = expf(x[c] - m) * inv;
            y[c] = v;
        }
    }
}

// invn[row] = 1 / max(||aug_row||, 1e-12)
__global__ __launch_bounds__(256) void rownorm_kernel(const float* __restrict__ aug, float* __restrict__ invn)
{
    const int row = blockIdx.x; const int t = threadIdx.x;
    f32x4 v = *(const f32x4*)(aug + (size_t)row * 1024 + t * 4);
    float s = v[0]*v[0] + v[1]*v[1] + v[2]*v[2] + v[3]*v[3];
    #pragma unroll
    for (int off = 32; off > 0; off >>= 1) s += __shfl_down(s, off, 64);
    __shared__ float ws4[4];
    const int lane = t & 63, wid = t >> 6;
    if (lane == 0) ws4[wid] = s;
    __syncthreads();
    if (t == 0) {
        float tot = ws4[0] + ws4[1] + ws4[2] + ws4[3];
        invn[row] = 1.0f / fmaxf(sqrtf(tot), 1e-12f);
    }
}

// plain row softmax over 1000
__global__ __launch_bounds__(256) void softmax2_kernel(const float* __restrict__ o2, float* __restrict__ out)
{
    const int row = blockIdx.x; const int t = threadIdx.x;
    const float* x = o2 + (size_t)row * 1000;
    float* y = out + (size_t)row * 1000;
    float m = -1e30f;
    for (int c = t; c < 1000; c += 256) m = fmaxf(m, x[c]);
    #pragma unroll
    for (int off = 32; off > 0; off >>= 1) m = fmaxf(m, __shfl_down(m, off, 64));
    __shared__ float sm4[4]; __shared__ float s_m, s_s;
    const int lane = t & 63, wid = t >> 6;
    if (lane == 0) sm4[wid] = m;
    __syncthreads();
    if (t == 0) s_m = fmaxf(fmaxf(sm4[0], sm4[1]), fmaxf(sm4[2], sm4[3]));
    __syncthreads();
    m = s_m;
    float s = 0.f;
    for (int c = t; c < 1000; c += 256) s += expf(x[c] - m);
    #pragma unroll
    for (int off = 32; off > 0; off >>= 1) s += __shfl_down(s, off, 64);
    if (lane == 0) sm4[wid] = s;
    __syncthreads();
    if (t == 0) s_s = sm4[0] + sm4[1] + sm4[2] + sm4[3];
    __syncthreads();
    const float inv = 1.0f / s_s;
    for (int c = t; c < 1000; c += 256) y[c] = expf(x[c] - m) * inv;
}

extern "C" void kernel_launch(void* const* d_in, const int* in_sizes, int n_in,
                              void* d_out, int out_size, void* d_ws, size_t ws_size,
                              hipStream_t stream)
{
    const float* features = (const float*)d_in[0];  // [8192,2048]
    const float* W_b      = (const float*)d_in[1];  // [1024,2048]
    const float* b_b      = (const float*)d_in[2];  // [1024]
    const float* W1       = (const float*)d_in[3];  // [1000,1024]
    const float* W2       = (const float*)d_in[4];  // [1000,1024]
    const float* centroid = (const float*)d_in[5];  // [1000,1024]

    float* out  = (float*)d_out;
    float* feats = out;                   // [8192,1024]
    float* aug   = out + 8388608;         // [8192,1024]
    float* o1    = out + 16777216;        // [8192,1000]
    float* o2    = out + 24969216;        // [8192,1000]
    float* smx   = out + 33161216;        // [8192,1000]
    float* sm1   = out + 24969216;        // scratch [8192,1024] (o2+smx slots)
    float* cT    = out + 33357824;        // scratch [1024,1024]
    float* invn  = out + 34406400;        // scratch [8192]

    dim3 g(8, 64);  // N-tiles x M-tiles (128x128)

    centroidT_kernel<<<4096, 256, 0, stream>>>(centroid, cT);
    // feats = F @ W_b^T + b_b   (fp16x2)
    gemm_kernel<1><<<g, 256, 0, stream>>>(features, 2048, W_b, 2048, 1024, 2048,
                                          feats, 1024, 1024, b_b, nullptr);
    // o1 = feats @ W1^T         (fp16x2, argmax-critical)
    gemm_kernel<2><<<g, 256, 0, stream>>>(feats, 1024, W1, 1024, 1000, 1024,
                                          o1, 1000, 1000, nullptr, nullptr);
    masksm_kernel<<<8192, 256, 0, stream>>>(o1, sm1);
    // aug = sm1 @ cT^T + feats  (fp16x1; cT is centroid^T so this is sm1@centroid)
    gemm_kernel<3><<<g, 256, 0, stream>>>(sm1, 1024, cT, 1024, 1024, 1024,
                                          aug, 1024, 1024, feats, nullptr);
    rownorm_kernel<<<8192, 256, 0, stream>>>(aug, invn);
    // o2 = (aug*invn) @ W2^T * 20
    gemm_kernel<4><<<g, 256, 0, stream>>>(aug, 1024, W2, 1024, 1000, 1024,
                                          o2, 1000, 1000, nullptr, invn);
    softmax2_kernel<<<8192, 256, 0, stream>>>(o2, smx);
}

// Round 2
// 310.962 us; speedup vs baseline: 2.6668x; 2.6668x over previous
//
#include <hip/hip_runtime.h>
#include <cmath>

// ---------------------------------------------------------------------------
// Classifier pipeline, fp16x2 split-precision MFMA, m97-style GEMM structure.
//
// d_out byte layout (total 165,412,864 B):
//   feats [8192,1024] f32 @ 0
//   aug   [8192,1024] f32 @ 33,554,432
//   o1    [8192,1000] f32 @ 67,108,864   (ends 99,876,864)
//   o2    [8192,1000] f32 @ 99,876,864   (ends 132,644,864)
//   smx   [8192,1000] f32 @ 132,644,864
//
// Scratch (dead-region hosted, lifetime-checked):
//   fh   fp16[8192*2048] @  67,108,864  [conv .. GEMM1]
//   fl   fp16[8192*2048] @ 100,663,296  [conv .. GEMM1]
//   wbh  fp16[1024*2048] @ 134,217,728  [conv .. GEMM1]
//   wbl  fp16[1024*2048] @ 138,412,032  [conv .. GEMM1]
//   fetsh fp16[8192*1024]@  33,554,432  [GEMM1 .. GEMM2]   (aug slot)
//   fetsl fp16[8192*1024]@  50,331,648  [GEMM1 .. GEMM2]
//   w1h  fp16[1024*1024] @ 142,606,336  [conv .. GEMM2]
//   w1l  fp16[1024*1024] @ 144,703,488  [conv .. GEMM2]
//   sm1h fp16[8192*1024] @  99,876,864  [masksm .. GEMM3]  (o2 slot)
//   cth  fp16[1024*1024] @ 116,654,080  [post-GEMM1 .. GEMM3]
//   w2h  fp16[1024*1024] @ 132,644,864  [post-GEMM1 .. GEMM4]
//   xh   fp16[8192*1024] @ 146,800,640  [rownorm .. GEMM4]
// ---------------------------------------------------------------------------

typedef _Float16 h8 __attribute__((ext_vector_type(8)));
typedef _Float16 h4 __attribute__((ext_vector_type(4)));
typedef float f32x4 __attribute__((ext_vector_type(4)));

__device__ __forceinline__ void gload_lds16(const _Float16* g, _Float16* l) {
    __builtin_amdgcn_global_load_lds(
        (const __attribute__((address_space(1))) void*)g,
        (__attribute__((address_space(3))) void*)l, 16, 0, 0);
}

// MODE 1: C = A@B^T + bias(aux); also write Ch/Cl fp16 split   [fp16x2]
// MODE 2: C = A@B^T, cols<nC                                   [fp16x2]
// MODE 3: C = A@B^T + aux[row,col]                             [fp16x1]
// MODE 4: C = A@B^T * 20, cols<nC                              [fp16x1]
template <int MODE>
__global__ __launch_bounds__(256, 2) void gemm16(
    const _Float16* __restrict__ Ah, const _Float16* __restrict__ Al, int lda,
    const _Float16* __restrict__ Bh, const _Float16* __restrict__ Bl, int ldb,
    int K,
    float* __restrict__ C, int ldc, int nC,
    const float* __restrict__ aux,
    _Float16* __restrict__ Ch, _Float16* __restrict__ Cl)
{
    constexpr bool P2 = (MODE <= 2);
    __shared__ _Float16 sAh[128 * 64];
    __shared__ _Float16 sBh[128 * 64];
    __shared__ _Float16 sAl[P2 ? 128 * 64 : 8];
    __shared__ _Float16 sBl[P2 ? 128 * 64 : 8];

    const int t = threadIdx.x;
    const int lane = t & 63, wid = t >> 6;
    const int row0 = blockIdx.y * 128, col0 = blockIdx.x * 128;
    const int wr = wid >> 1, wc = wid & 1;     // 2x2 waves -> 64x64 out each
    const int fr = lane & 15;                  // fragment row/col
    const int fk = (lane >> 4) * 8;            // fragment k offset (halves)
    const int srow = lane >> 3;                // staging: 8 lanes per row
    const int scol = (lane & 7) * 8;           // 8 halves (16B) per lane

    f32x4 acc[4][4] = {};
    f32x4 accc[4][4] = {};                     // cross terms (x2048); DCE'd if !P2

    for (int k0 = 0; k0 < K; k0 += 64) {
        // ---- stage via global_load_lds (wave-uniform LDS base + lane*16B) ----
        #pragma unroll
        for (int j = 0; j < 4; ++j) {
            int i = wid * 4 + j;                       // issue 0..15: rows i*8..i*8+7
            int r = i * 8 + srow;
            const size_t ga = (size_t)(row0 + r) * lda + k0 + scol;
            const size_t gb = (size_t)(col0 + r) * ldb + k0 + scol;
            gload_lds16(Ah + ga, &sAh[i * 512]);
            gload_lds16(Bh + gb, &sBh[i * 512]);
            if constexpr (P2) {
                gload_lds16(Al + ga, &sAl[i * 512]);
                gload_lds16(Bl + gb, &sBl[i * 512]);
            }
        }
        __syncthreads();   // compiler emits vmcnt(0) drain before s_barrier
        // ---- compute ----
        #pragma unroll
        for (int ks = 0; ks < 2; ++ks) {
            h8 ah[4], al[4];
            #pragma unroll
            for (int mf = 0; mf < 4; ++mf) {
                int rr = wr * 64 + mf * 16 + fr;
                ah[mf] = *(const h8*)&sAh[rr * 64 + ks * 32 + fk];
                if constexpr (P2) al[mf] = *(const h8*)&sAl[rr * 64 + ks * 32 + fk];
            }
            #pragma unroll
            for (int nf = 0; nf < 4; ++nf) {
                int cc = wc * 64 + nf * 16 + fr;
                h8 bh = *(const h8*)&sBh[cc * 64 + ks * 32 + fk];
                h8 bl;
                if constexpr (P2) bl = *(const h8*)&sBl[cc * 64 + ks * 32 + fk];
                #pragma unroll
                for (int mf = 0; mf < 4; ++mf) {
                    acc[mf][nf] = __builtin_amdgcn_mfma_f32_16x16x32_f16(ah[mf], bh, acc[mf][nf], 0, 0, 0);
                    if constexpr (P2) {
                        accc[mf][nf] = __builtin_amdgcn_mfma_f32_16x16x32_f16(ah[mf], bl, accc[mf][nf], 0, 0, 0);
                        accc[mf][nf] = __builtin_amdgcn_mfma_f32_16x16x32_f16(al[mf], bh, accc[mf][nf], 0, 0, 0);
                    }
                }
            }
        }
        __syncthreads();
    }
    // ---- epilogue (C/D: col=lane&15, row=(lane>>4)*4+j) ----
    #pragma unroll
    for (int mf = 0; mf < 4; ++mf) {
        #pragma unroll
        for (int nf = 0; nf < 4; ++nf) {
            f32x4 v = acc[mf][nf];
            if constexpr (P2) v = v + accc[mf][nf] * (1.0f / 2048.0f);
            int gcol = col0 + wc * 64 + nf * 16 + fr;
            int rbase = row0 + wr * 64 + mf * 16 + (lane >> 4) * 4;
            #pragma unroll
            for (int j = 0; j < 4; ++j) {
                int grow = rbase + j;
                float val = v[j];
                if constexpr (MODE == 1) val += aux[gcol];
                if constexpr (MODE == 3) val += aux[(size_t)grow * 1024 + gcol];
                if constexpr (MODE == 4) val *= 20.0f;
                if (gcol < nC) {
                    C[(size_t)grow * ldc + gcol] = val;
                    if constexpr (MODE == 1) {
                        _Float16 h = (_Float16)val;
                        Ch[(size_t)grow * 1024 + gcol] = h;
                        Cl[(size_t)grow * 1024 + gcol] = (_Float16)((val - (float)h) * 2048.0f);
                    }
                }
            }
        }
    }
}

// fp32 -> fp16 hi/lo split (lo scaled x2048 to stay in fp16 normal range)
__global__ void split_kernel(const float* __restrict__ src,
                             _Float16* __restrict__ hi, _Float16* __restrict__ lo, int n4)
{
    for (int i = blockIdx.x * 256 + threadIdx.x; i < n4; i += gridDim.x * 256) {
        f32x4 v = ((const f32x4*)src)[i];
        h4 h, l;
        #pragma unroll
        for (int j = 0; j < 4; ++j) {
            _Float16 hh = (_Float16)v[j];
            h[j] = hh;
            l[j] = (_Float16)((v[j] - (float)hh) * 2048.0f);
        }
        ((h4*)hi)[i] = h;
        ((h4*)lo)[i] = l;
    }
}

// fp32 [nrows,1024] -> fp16 hi(/lo) padded to [1024,1024] (rows>=nrows zero)
template <bool LO>
__global__ void padsplit_kernel(const float* __restrict__ src,
                                _Float16* __restrict__ hi, _Float16* __restrict__ lo, int nrows)
{
    for (int i = blockIdx.x * 256 + threadIdx.x; i < 1024 * 256; i += gridDim.x * 256) {
        int r = i >> 8;
        f32x4 v = {0.f, 0.f, 0.f, 0.f};
        if (r < nrows) v = ((const f32x4*)src)[i];
        h4 h, l;
        #pragma unroll
        for (int j = 0; j < 4; ++j) {
            _Float16 hh = (_Float16)v[j];
            h[j] = hh;
            if constexpr (LO) l[j] = (_Float16)((v[j] - (float)hh) * 2048.0f);
        }
        ((h4*)hi)[i] = h;
        if constexpr (LO) ((h4*)lo)[i] = l;
    }
}

// cT[n][k] = k<1000 ? fp16(centroid[k][n]) : 0   (LDS-tiled transpose)
__global__ __launch_bounds__(256) void ctrans_kernel(const float* __restrict__ centroid,
                                                     _Float16* __restrict__ cT)
{
    __shared__ float tile[32][33];
    const int t = threadIdx.x;
    const int tx = t & 31, ty = t >> 5;
    const int k0 = blockIdx.y * 32, n0 = blockIdx.x * 32;
    #pragma unroll
    for (int p = 0; p < 4; ++p) {
        int k = k0 + ty + p * 8;
        tile[ty + p * 8][tx] = (k < 1000) ? centroid[(size_t)k * 1024 + n0 + tx] : 0.0f;
    }
    __syncthreads();
    #pragma unroll
    for (int p = 0; p < 4; ++p) {
        int n = n0 + ty + p * 8;
        cT[(size_t)n * 1024 + k0 + tx] = (_Float16)tile[tx][ty + p * 8];
    }
}

// mask_mechanism: argmax -> masked softmax; writes fp16 [8192,1024] (pad zeros)
__global__ __launch_bounds__(256) void masksm_kernel(const float* __restrict__ o1,
                                                     _Float16* __restrict__ sm)
{
    const int row = blockIdx.x;
    const int t = threadIdx.x;
    const float* x = o1 + (size_t)row * 1000;
    _Float16* y = sm + (size_t)row * 1024;

    float bv = -1e30f; int bi = 0;
    for (int c = t; c < 1000; c += 256) {
        float v = x[c];
        if (v > bv) { bv = v; bi = c; }       // first-occurrence argmax
    }
    #pragma unroll
    for (int off = 32; off > 0; off >>= 1) {
        float ov = __shfl_down(bv, off, 64);
        int   oi = __shfl_down(bi, off, 64);
        if (ov > bv || (ov == bv && oi < bi)) { bv = ov; bi = oi; }
    }
    __shared__ float wv[4]; __shared__ int wi[4];
    __shared__ float s_m, s_tot; __shared__ int s_p;
    const int lane = t & 63, wid = t >> 6;
    if (lane == 0) { wv[wid] = bv; wi[wid] = bi; }
    __syncthreads();
    if (t == 0) {
        float mv = wv[0]; int mi = wi[0];
        for (int w = 1; w < 4; ++w)
            if (wv[w] > mv || (wv[w] == mv && wi[w] < mi)) { mv = wv[w]; mi = wi[w]; }
        s_p = mi; s_m = mv;
    }
    __syncthreads();
    const int p = s_p; const float m = s_m;
    if (p >= 500) {
        for (int c = t; c < 1024; c += 256) y[c] = (c == p) ? (_Float16)1.0f : (_Float16)0.0f;
    } else {
        float s = 0.f;
        for (int c = t; c < 1000; c += 256)
            if (c == p || c >= 500) s += expf(x[c] - m);
        #pragma unroll
        for (int off = 32; off > 0; off >>= 1) s += __shfl_down(s, off, 64);
        if (lane == 0) wv[wid] = s;
        __syncthreads();
        if (t == 0) s_tot = wv[0] + wv[1] + wv[2] + wv[3];
        __syncthreads();
        const float inv = 1.0f / s_tot;
        for (int c = t; c < 1024; c += 256) {
            float v = 0.f;
            if (c < 1000 && (c == p || c >= 500)) v = expf(x[c] - m) * inv;
            y[c] = (_Float16)v;
        }
    }
}

// fused: invn = 1/max(||aug_row||,eps); xh = fp16(aug * invn)
__global__ __launch_bounds__(256) void rownorm_x_kernel(const float* __restrict__ aug,
                                                        _Float16* __restrict__ xh)
{
    const int row = blockIdx.x; const int t = threadIdx.x;
    f32x4 v = *((const f32x4*)(aug + (size_t)row * 1024) + t);
    float s = v[0]*v[0] + v[1]*v[1] + v[2]*v[2] + v[3]*v[3];
    #pragma unroll
    for (int off = 32; off > 0; off >>= 1) s += __shfl_down(s, off, 64);
    __shared__ float ws4[4]; __shared__ float s_inv;
    const int lane = t & 63, wid = t >> 6;
    if (lane == 0) ws4[wid] = s;
    __syncthreads();
    if (t == 0) {
        float tot = ws4[0] + ws4[1] + ws4[2] + ws4[3];
        s_inv = 1.0f / fmaxf(sqrtf(tot), 1e-12f);
    }
    __syncthreads();
    const float inv = s_inv;
    h4 h;
    #pragma unroll
    for (int j = 0; j < 4; ++j) h[j] = (_Float16)(v[j] * inv);
    *((h4*)(xh + (size_t)row * 1024) + t) = h;
}

// plain row softmax over 1000
__global__ __launch_bounds__(256) void softmax2_kernel(const float* __restrict__ o2,
                                                       float* __restrict__ out)
{
    const int row = blockIdx.x; const int t = threadIdx.x;
    const float* x = o2 + (size_t)row * 1000;
    float* y = out + (size_t)row * 1000;
    float m = -1e30f;
    for (int c = t; c < 1000; c += 256) m = fmaxf(m, x[c]);
    #pragma unroll
    for (int off = 32; off > 0; off >>= 1) m = fmaxf(m, __shfl_down(m, off, 64));
    __shared__ float sm4[4]; __shared__ float s_m, s_s;
    const int lane = t & 63, wid = t >> 6;
    if (lane == 0) sm4[wid] = m;
    __syncthreads();
    if (t == 0) s_m = fmaxf(fmaxf(sm4[0], sm4[1]), fmaxf(sm4[2], sm4[3]));
    __syncthreads();
    m = s_m;
    float s = 0.f;
    for (int c = t; c < 1000; c += 256) s += expf(x[c] - m);
    #pragma unroll
    for (int off = 32; off > 0; off >>= 1) s += __shfl_down(s, off, 64);
    if (lane == 0) sm4[wid] = s;
    __syncthreads();
    if (t == 0) s_s = sm4[0] + sm4[1] + sm4[2] + sm4[3];
    __syncthreads();
    const float inv = 1.0f / s_s;
    for (int c = t; c < 1000; c += 256) y[c] = expf(x[c] - m) * inv;
}

extern "C" void kernel_launch(void* const* d_in, const int* in_sizes, int n_in,
                              void* d_out, int out_size, void* d_ws, size_t ws_size,
                              hipStream_t stream)
{
    const float* features = (const float*)d_in[0];  // [8192,2048]
    const float* W_b      = (const float*)d_in[1];  // [1024,2048]
    const float* b_b      = (const float*)d_in[2];  // [1024]
    const float* W1       = (const float*)d_in[3];  // [1000,1024]
    const float* W2       = (const float*)d_in[4];  // [1000,1024]
    const float* centroid = (const float*)d_in[5];  // [1000,1024]

    char* base = (char*)d_out;
    float* feats = (float*)(base);
    float* aug   = (float*)(base + 33554432);
    float* o1    = (float*)(base + 67108864);
    float* o2    = (float*)(base + 99876864);
    float* smx   = (float*)(base + 132644864);

    _Float16* fh    = (_Float16*)(base + 67108864);
    _Float16* fl    = (_Float16*)(base + 100663296);
    _Float16* wbh   = (_Float16*)(base + 134217728);
    _Float16* wbl   = (_Float16*)(base + 138412032);
    _Float16* fetsh = (_Float16*)(base + 33554432);
    _Float16* fetsl = (_Float16*)(base + 50331648);
    _Float16* w1h   = (_Float16*)(base + 142606336);
    _Float16* w1l   = (_Float16*)(base + 144703488);
    _Float16* sm1h  = (_Float16*)(base + 99876864);
    _Float16* cth   = (_Float16*)(base + 116654080);
    _Float16* w2h   = (_Float16*)(base + 132644864);
    _Float16* xh    = (_Float16*)(base + 146800640);

    dim3 g(8, 64);  // N-tiles x M-tiles (128x128)

    // conversions with no GEMM dependency
    split_kernel<<<2048, 256, 0, stream>>>(features, fh, fl, 4194304);
    split_kernel<<<2048, 256, 0, stream>>>(W_b, wbh, wbl, 524288);
    padsplit_kernel<true><<<1024, 256, 0, stream>>>(W1, w1h, w1l, 1000);

    // GEMM1: feats = F@W_b^T + b_b (fp16x2); epilogue also emits feats hi/lo
    gemm16<1><<<g, 256, 0, stream>>>(fh, fl, 2048, wbh, wbl, 2048, 2048,
                                     feats, 1024, 1024, b_b, fetsh, fetsl);

    // these regions overlap fh/fl/wbh (dead after GEMM1) -> launch after GEMM1
    ctrans_kernel<<<dim3(32, 32), 256, 0, stream>>>(centroid, cth);
    padsplit_kernel<false><<<1024, 256, 0, stream>>>(W2, w2h, nullptr, 1000);

    // GEMM2: o1 = feats@W1^T (fp16x2, argmax-critical)
    gemm16<2><<<g, 256, 0, stream>>>(fetsh, fetsl, 1024, w1h, w1l, 1024, 1024,
                                     o1, 1000, 1000, nullptr, nullptr, nullptr);

    masksm_kernel<<<8192, 256, 0, stream>>>(o1, sm1h);

    // GEMM3: aug = sm1@centroid + feats (fp16x1)
    gemm16<3><<<g, 256, 0, stream>>>(sm1h, nullptr, 1024, cth, nullptr, 1024, 1024,
                                     aug, 1024, 1024, feats, nullptr, nullptr);

    rownorm_x_kernel<<<8192, 256, 0, stream>>>(aug, xh);

    // GEMM4: o2 = x@W2^T * 20 (fp16x1)
    gemm16<4><<<g, 256, 0, stream>>>(xh, nullptr, 1024, w2h, nullptr, 1024, 1024,
                                     o2, 1000, 1000, nullptr, nullptr, nullptr);

    softmax2_kernel<<<8192, 256, 0, stream>>>(o2, smx);
}